// Round 6
// baseline (87.175 us; speedup 1.0000x reference)
//
#include <hip/hip_runtime.h>
#include <hip/hip_bf16.h>

// Problem constants
#define Bn   4
#define Cn   256
#define Dn   32
#define Hn   64
#define Wn   64
#define Kt   64          // top-k
#define PROJ 512
#define DHW  (Dn*Hn*Wn)  // 131072
#define HW   (Hn*Wn)     // 4096
#define VECLEN (Kt*Cn)   // 16384 per batch

#define NBIN    4096     // histogram on top 12 bits of sortable key
#define CANDMAX 4096     // per-batch candidate buffer (expected ~100-300 used)

// ---- workspace layout (bytes) ----
// hist: u16 [Bn*8][NBIN] private per-sub copies = 256 KB (no zeroing needed)
#define WS_HIST_OFF 0
#define WS_CNT_OFF  (256*1024)   // int cnt[Bn]
#define WS_IDX_OFF  (257*1024)   // int topk_idx[Bn*Kt] = 1 KB
#define WS_CAND_OFF (260*1024)   // u64 cand[Bn][CANDMAX] = 128 KB
#define WS_VEC_OFF  (392*1024)   // float vec[Bn][VECLEN] = 256 KB

// ---- d_out layout (float32 elements) ----
#define OUT_SCORES 768
#define OUT_FEAT   1024

__device__ __forceinline__ unsigned f2sortable(float f) {
    unsigned u = __float_as_uint(f);
    return (u & 0x80000000u) ? ~u : (u | 0x80000000u);
}
__device__ __forceinline__ float sortable2f(unsigned u) {
    unsigned orig = (u & 0x80000000u) ? (u & 0x7FFFFFFFu) : ~u;
    return __uint_as_float(orig);
}

// ---------------- Pass 1: per-sub private histograms (no pre-zero) -------
__global__ __launch_bounds__(256) void hist_kernel(
        const float* __restrict__ score, unsigned short* __restrict__ hist,
        int* __restrict__ cnt) {
    __shared__ int lh[NBIN];
    const int blk = blockIdx.x;        // Bn*8; blk = b*8+sub
    const int b   = blk >> 3;
    const int sub = blk & 7;
    const int tid = threadIdx.x;

    for (int i = tid; i < NBIN; i += 256) lh[i] = 0;
    __syncthreads();

    const float4* src = (const float4*)(score + (size_t)b * DHW) + sub * 4096;
    for (int i = tid; i < 4096; i += 256) {
        float4 v = src[i];
        atomicAdd(&lh[f2sortable(v.x) >> 20], 1);
        atomicAdd(&lh[f2sortable(v.y) >> 20], 1);
        atomicAdd(&lh[f2sortable(v.z) >> 20], 1);
        atomicAdd(&lh[f2sortable(v.w) >> 20], 1);
    }
    __syncthreads();

    unsigned short* gh = hist + ((size_t)blk << 12);
    for (int i = tid; i < NBIN; i += 256)
        gh[i] = (unsigned short)lh[i];      // counts <= 16384, fits u16
    if (blk == 0 && tid < Bn) cnt[tid] = 0;
}

// ---------------- Pass 2: find threshold bin, compact candidates ---------
__global__ __launch_bounds__(256) void compact_kernel(
        const float* __restrict__ score, const unsigned short* __restrict__ hist,
        unsigned long long* __restrict__ cand, int* __restrict__ cnt) {
    __shared__ int sh[NBIN];
    __shared__ int partial[256];
    __shared__ int thrBin;
    const int blk = blockIdx.x;
    const int b   = blk >> 3;
    const int sub = blk & 7;
    const int tid = threadIdx.x;
    const unsigned short* h = hist + ((size_t)(b * 8) << 12);

    // sum the 8 per-sub copies (L2-hot) into LDS
    for (int i = tid; i < NBIN; i += 256) {
        int s = 0;
        #pragma unroll
        for (int ss = 0; ss < 8; ++ss) s += h[(ss << 12) + i];
        sh[i] = s;
    }
    __syncthreads();

    // suffix scan from top bin: chunk t covers bins [4080-16t, 4095-16t]
    {
        int base = NBIN - 16 - 16 * tid;
        int s = 0;
        #pragma unroll
        for (int i = 0; i < 16; ++i) s += sh[base + i];
        partial[tid] = s;
    }
    __syncthreads();
    if (tid == 0) {
        int cum = 0, T = 0;
        for (int j = 0; j < 256; ++j) {
            if (cum + partial[j] >= Kt) {
                int bb = NBIN - 1 - 16 * j;
                for (int i = 0; i < 16; ++i) {
                    cum += sh[bb - i];
                    if (cum >= Kt) { T = bb - i; break; }
                }
                break;
            }
            cum += partial[j];
        }
        thrBin = T;
    }
    __syncthreads();
    const unsigned thr = (unsigned)thrBin;

    const float4* src = (const float4*)(score + (size_t)b * DHW) + sub * 4096;
    unsigned long long* cb = cand + (size_t)b * CANDMAX;
    for (int i = tid; i < 4096; i += 256) {
        float4 v = src[i];
        unsigned gbase = (unsigned)((sub * 4096 + i) * 4);
        float vals[4] = {v.x, v.y, v.z, v.w};
        #pragma unroll
        for (int l = 0; l < 4; ++l) {
            unsigned u = f2sortable(vals[l]);
            if ((u >> 20) >= thr) {
                int pos = atomicAdd(&cnt[b], 1);
                if (pos < CANDMAX)
                    cb[pos] = ((unsigned long long)u << 32) |
                              (0xFFFFFFFFu - (gbase + l));
            }
        }
    }
}

// ---------------- Pass 3: sort small candidate list, emit top-64 ---------
__global__ __launch_bounds__(512) void final_kernel(
        const unsigned long long* __restrict__ cand, const int* __restrict__ cnt,
        float* __restrict__ out, int* __restrict__ topk_idx) {
    __shared__ unsigned long long keys[CANDMAX];
    const int b   = blockIdx.x;
    const int tid = threadIdx.x;

    int n = cnt[b];
    if (n > CANDMAX) n = CANDMAX;
    int P = 64;
    while (P < n) P <<= 1;

    const unsigned long long* cb = cand + (size_t)b * CANDMAX;
    for (int i = tid; i < P; i += 512)
        keys[i] = (i < n) ? cb[i] : 0ULL;
    __syncthreads();

    for (int k = 2; k <= P; k <<= 1) {
        for (int j = k >> 1; j > 0; j >>= 1) {
            for (int i = tid; i < P; i += 512) {
                int ixj = i ^ j;
                if (ixj > i) {
                    unsigned long long a = keys[i], c = keys[ixj];
                    bool desc = ((i & k) == 0);
                    if (desc ? (a < c) : (a > c)) { keys[i] = c; keys[ixj] = a; }
                }
            }
            __syncthreads();
        }
    }

    if (tid < Kt) {
        unsigned long long kk = keys[tid];
        float score = sortable2f((unsigned)(kk >> 32));
        unsigned gidx = 0xFFFFFFFFu - (unsigned)(kk & 0xFFFFFFFFu);
        int z = (int)(gidx >> 12);
        int y = (int)((gidx >> 6) & 63);
        int x = (int)(gidx & 63);
        int o = (b * Kt + tid) * 3;
        out[o + 0] = (float)z;
        out[o + 1] = (float)y;
        out[o + 2] = (float)x;
        out[OUT_SCORES + b * Kt + tid] = score;
        topk_idx[b * Kt + tid] = (int)gidx;
    }
}

// ---------------- Gather: masked patch average per (b,k,c) ---------------
// grid = Bn*Cn = 1024 blocks x 256 threads (4 waves/SIMD occupancy-wise).
// lane = k (diverse DRAM addresses, round-4 win); the 4 waves (r) split the
// 25 patch rows round-robin (<=7 rows x <=2 float4 each), LDS 4-way reduce.
__global__ __launch_bounds__(256) void gather_kernel(
        const float* __restrict__ fm, const int* __restrict__ topk_idx,
        float* __restrict__ vec) {
    __shared__ float red[4][Kt];
    const int blk = blockIdx.x;        // Bn*Cn = 1024
    const int b   = blk >> 8;
    const int c   = blk & 255;
    const int tid = threadIdx.x;
    const int k   = tid & 63;          // lane = k
    const int r   = tid >> 6;          // 0..3 row-group

    const int idx = topk_idx[b * Kt + k];
    const int z = idx >> 12;
    const int y = (idx >> 6) & 63;
    const int x = idx & 63;
    const int z0 = max(z - 2, 0), y0 = max(y - 2, 0), x0 = max(x - 2, 0);
    const int nz = min(5, Dn - z0), ny = min(5, Hn - y0), nx = min(5, Wn - x0);
    const int xe = x0 + nx;            // <= 64
    const int a0 = x0 & ~3;
    const bool need2 = (a0 + 4) < xe;

    float m[8];
    #pragma unroll
    for (int j = 0; j < 8; ++j) {
        int e = a0 + j;
        m[j] = (e >= x0 && e < xe) ? 1.f : 0.f;
    }

    const float* base = fm + ((size_t)(b * Cn + c)) * DHW
                           + (size_t)z0 * HW + (size_t)y0 * Wn;
    float s0 = 0.f, s1 = 0.f;
    #pragma unroll
    for (int u = 0; u < 7; ++u) {
        int rr = r + 4 * u;
        if (rr < 25) {
            int iz = rr / 5, iy = rr % 5;
            if (iz < nz && iy < ny) {          // per-lane predication
                const float* row = base + iz * HW + iy * Wn;
                float4 v0 = *(const float4*)(row + a0);
                s0 = fmaf(v0.x, m[0], s0);
                s0 = fmaf(v0.y, m[1], s0);
                s0 = fmaf(v0.z, m[2], s0);
                s0 = fmaf(v0.w, m[3], s0);
                if (need2) {
                    float4 v1 = *(const float4*)(row + a0 + 4);
                    s1 = fmaf(v1.x, m[4], s1);
                    s1 = fmaf(v1.y, m[5], s1);
                    s1 = fmaf(v1.z, m[6], s1);
                    s1 = fmaf(v1.w, m[7], s1);
                }
            }
        }
    }
    red[r][k] = s0 + s1;
    __syncthreads();
    if (r == 0) {
        float t = (red[0][k] + red[1][k]) + (red[2][k] + red[3][k]);
        vec[((size_t)(b * Kt + k) << 8) + c] = t / (float)(nz * ny * nx);
    }
}

// ---------------- GEMV: feature = vec @ Wp^T + b --------------------------
__global__ __launch_bounds__(256) void gemv_kernel(
        const float* __restrict__ vec, const float* __restrict__ Wp,
        const float* __restrict__ bias, float* __restrict__ out) {
    const int p   = blockIdx.x;        // PROJ
    const int tid = threadIdx.x;       // 256
    const float4* w4 = (const float4*)(Wp + (size_t)p * VECLEN);

    float acc[Bn] = {0.f, 0.f, 0.f, 0.f};
    for (int i = tid; i < VECLEN / 4; i += 256) {
        float4 wv = w4[i];
        #pragma unroll
        for (int bb = 0; bb < Bn; ++bb) {
            float4 vv = ((const float4*)(vec + bb * VECLEN))[i];
            acc[bb] += wv.x * vv.x + wv.y * vv.y + wv.z * vv.z + wv.w * vv.w;
        }
    }

    __shared__ float red[4][Bn];
    const int lane = tid & 63, wave = tid >> 6;
    #pragma unroll
    for (int bb = 0; bb < Bn; ++bb) {
        float v = acc[bb];
        #pragma unroll
        for (int off = 32; off > 0; off >>= 1) v += __shfl_down(v, off, 64);
        if (lane == 0) red[wave][bb] = v;
    }
    __syncthreads();
    if (tid < Bn) {
        int bb = tid;
        float t = red[0][bb] + red[1][bb] + red[2][bb] + red[3][bb];
        out[OUT_FEAT + bb * PROJ + p] = t + bias[p];
    }
}

extern "C" void kernel_launch(void* const* d_in, const int* in_sizes, int n_in,
                              void* d_out, int out_size, void* d_ws, size_t ws_size,
                              hipStream_t stream) {
    const float* fm    = (const float*)d_in[0];
    const float* score = (const float*)d_in[1];
    const float* Wp    = (const float*)d_in[2];
    const float* bias  = (const float*)d_in[3];
    float* out = (float*)d_out;

    char* ws = (char*)d_ws;
    unsigned short* hist = (unsigned short*)(ws + WS_HIST_OFF);
    int*   cand_cnt = (int*)(ws + WS_CNT_OFF);
    int*   topk_idx = (int*)(ws + WS_IDX_OFF);
    unsigned long long* cand = (unsigned long long*)(ws + WS_CAND_OFF);
    float* vec      = (float*)(ws + WS_VEC_OFF);

    hist_kernel<<<Bn * 8, 256, 0, stream>>>(score, hist, cand_cnt);
    compact_kernel<<<Bn * 8, 256, 0, stream>>>(score, hist, cand, cand_cnt);
    final_kernel<<<Bn, 512, 0, stream>>>(cand, cand_cnt, out, topk_idx);
    gather_kernel<<<Bn * Cn, 256, 0, stream>>>(fm, topk_idx, vec);
    gemv_kernel<<<PROJ, 256, 0, stream>>>(vec, Wp, bias, out);
}

// Round 7
// 71.004 us; speedup vs baseline: 1.2277x; 1.2277x over previous
//
#include <hip/hip_runtime.h>
#include <hip/hip_bf16.h>

// Problem constants
#define Bn   4
#define Cn   256
#define Dn   32
#define Hn   64
#define Wn   64
#define Kt   64          // top-k
#define PROJ 512
#define DHW  (Dn*Hn*Wn)  // 131072
#define HW   (Hn*Wn)     // 4096
#define VECLEN (Kt*Cn)   // 16384 per batch

#define NBIN    4096     // fallback histogram bins (top 12 sortable bits)
#define CANDMAX 4096     // per-batch candidate buffer (expected ~180 used)
#define STATIC_THR 3.0f  // scores ~ N(0,1); top-64/131072 is ~3.24 sigma.
                         // >3.0 keeps ~177/batch (>=64 with ~9-sigma margin).
                         // If ever wrong, final_kernel falls back to an exact
                         // in-block recompute -- correctness never depends on it.

// ---- workspace layout (bytes) ----
#define WS_CNT_OFF  0            // int cnt[Bn]
#define WS_IDX_OFF  1024         // int topk_idx[Bn*Kt] = 1 KB
#define WS_CAND_OFF 4096         // u64 cand[Bn][CANDMAX] = 128 KB
#define WS_VEC_OFF  (256*1024)   // float vec[Bn][VECLEN] = 256 KB

// ---- d_out layout (float32 elements) ----
#define OUT_SCORES 768
#define OUT_FEAT   1024

__device__ __forceinline__ unsigned f2sortable(float f) {
    unsigned u = __float_as_uint(f);
    return (u & 0x80000000u) ? ~u : (u | 0x80000000u);
}
__device__ __forceinline__ float sortable2f(unsigned u) {
    unsigned orig = (u & 0x80000000u) ? (u & 0x7FFFFFFFu) : ~u;
    return __uint_as_float(orig);
}

// ---------------- Pass 1: static-threshold compact (full grid) -----------
// grid = Bn*64 = 256 blocks x 256 threads; each block streams 512 float4.
__global__ __launch_bounds__(256) void compact_kernel(
        const float* __restrict__ score, unsigned long long* __restrict__ cand,
        int* __restrict__ cnt) {
    const int blk = blockIdx.x;
    const int b   = blk >> 6;
    const int sub = blk & 63;
    const int tid = threadIdx.x;
    const unsigned thr = f2sortable(STATIC_THR);

    const float4* src = (const float4*)(score + (size_t)b * DHW) + sub * 512;
    unsigned long long* cb = cand + (size_t)b * CANDMAX;
    #pragma unroll
    for (int i = tid; i < 512; i += 256) {
        float4 v = src[i];
        unsigned gbase = (unsigned)((sub * 512 + i) * 4);
        float vals[4] = {v.x, v.y, v.z, v.w};
        #pragma unroll
        for (int l = 0; l < 4; ++l) {
            unsigned u = f2sortable(vals[l]);
            if (u >= thr) {
                int pos = atomicAdd(&cnt[b], 1);
                if (pos < CANDMAX)
                    cb[pos] = ((unsigned long long)u << 32) |
                              (0xFFFFFFFFu - (gbase + l));
            }
        }
    }
}

// ---------------- Pass 2: sort candidates, emit top-64 (w/ exact fallback)
__global__ __launch_bounds__(512) void final_kernel(
        const float* __restrict__ score,
        const unsigned long long* __restrict__ cand, const int* __restrict__ cnt,
        float* __restrict__ out, int* __restrict__ topk_idx) {
    __shared__ unsigned long long keys[CANDMAX];   // 32 KB
    __shared__ int lh[NBIN];                       // 16 KB (fallback only)
    __shared__ int partial[256];
    __shared__ int s_cnt, s_thr;
    const int b   = blockIdx.x;
    const int tid = threadIdx.x;

    int n = cnt[b];
    if (n >= Kt && n <= CANDMAX) {
        const unsigned long long* cb = cand + (size_t)b * CANDMAX;
        for (int i = tid; i < n; i += 512) keys[i] = cb[i];
    } else {
        // ---- exact fallback: hist -> threshold -> compact, in-block ----
        for (int i = tid; i < NBIN; i += 512) lh[i] = 0;
        if (tid == 0) s_cnt = 0;
        __syncthreads();
        const float4* src = (const float4*)(score + (size_t)b * DHW);
        for (int i = tid; i < DHW / 4; i += 512) {
            float4 v = src[i];
            atomicAdd(&lh[f2sortable(v.x) >> 20], 1);
            atomicAdd(&lh[f2sortable(v.y) >> 20], 1);
            atomicAdd(&lh[f2sortable(v.z) >> 20], 1);
            atomicAdd(&lh[f2sortable(v.w) >> 20], 1);
        }
        __syncthreads();
        if (tid < 256) {
            int base = NBIN - 16 - 16 * tid;
            int s = 0;
            #pragma unroll
            for (int i = 0; i < 16; ++i) s += lh[base + i];
            partial[tid] = s;
        }
        __syncthreads();
        if (tid == 0) {
            int cum = 0, T = 0;
            for (int j = 0; j < 256; ++j) {
                if (cum + partial[j] >= Kt) {
                    int bb = NBIN - 1 - 16 * j;
                    for (int i = 0; i < 16; ++i) {
                        cum += lh[bb - i];
                        if (cum >= Kt) { T = bb - i; break; }
                    }
                    break;
                }
                cum += partial[j];
            }
            s_thr = T;
        }
        __syncthreads();
        const unsigned thr = (unsigned)s_thr;
        for (int i = tid; i < DHW / 4; i += 512) {
            float4 v = src[i];
            float vals[4] = {v.x, v.y, v.z, v.w};
            #pragma unroll
            for (int l = 0; l < 4; ++l) {
                unsigned u = f2sortable(vals[l]);
                if ((u >> 20) >= thr) {
                    int pos = atomicAdd(&s_cnt, 1);
                    if (pos < CANDMAX)
                        keys[pos] = ((unsigned long long)u << 32) |
                                    (0xFFFFFFFFu - (unsigned)(4 * i + l));
                }
            }
        }
        __syncthreads();
        n = s_cnt;
        if (n > CANDMAX) n = CANDMAX;
    }

    int P = 64;
    while (P < n) P <<= 1;     // P <= 4096
    for (int i = tid; i < P; i += 512)
        if (i >= n) keys[i] = 0ULL;
    __syncthreads();

    // bitonic sort descending on unique 64-bit keys (deterministic output)
    for (int k = 2; k <= P; k <<= 1) {
        for (int j = k >> 1; j > 0; j >>= 1) {
            for (int i = tid; i < P; i += 512) {
                int ixj = i ^ j;
                if (ixj > i) {
                    unsigned long long a = keys[i], c = keys[ixj];
                    bool desc = ((i & k) == 0);
                    if (desc ? (a < c) : (a > c)) { keys[i] = c; keys[ixj] = a; }
                }
            }
            __syncthreads();
        }
    }

    if (tid < Kt) {
        unsigned long long kk = keys[tid];
        float sc = sortable2f((unsigned)(kk >> 32));
        unsigned gidx = 0xFFFFFFFFu - (unsigned)(kk & 0xFFFFFFFFu);
        int z = (int)(gidx >> 12);
        int y = (int)((gidx >> 6) & 63);
        int x = (int)(gidx & 63);
        int o = (b * Kt + tid) * 3;
        out[o + 0] = (float)z;
        out[o + 1] = (float)y;
        out[o + 2] = (float)x;
        out[OUT_SCORES + b * Kt + tid] = sc;
        topk_idx[b * Kt + tid] = (int)gidx;
    }
}

// ---------------- Gather: masked patch average per (b,k,c) ---------------
// Round-4 form (best measured): lane = k -> a wave's 64 simultaneous
// addresses are scattered patch locations (diverse DRAM channel/bank bits).
// Each thread computes the full 125-tap clamped sum for its (b,k,c) with
// ~50 independent float4 loads (deep MLP). grid = Bn*64 x 256.
__global__ __launch_bounds__(256) void gather_kernel(
        const float* __restrict__ fm, const int* __restrict__ topk_idx,
        float* __restrict__ vec) {
    const int blk = blockIdx.x;        // Bn*64 = 256
    const int b   = blk >> 6;
    const int cg  = blk & 63;
    const int tid = threadIdx.x;
    const int k   = tid & 63;          // lane = k
    const int c   = cg * 4 + (tid >> 6);

    const int idx = topk_idx[b * Kt + k];
    const int z = idx >> 12;
    const int y = (idx >> 6) & 63;
    const int x = idx & 63;
    const int z0 = max(z - 2, 0), y0 = max(y - 2, 0), x0 = max(x - 2, 0);
    const int nz = min(5, Dn - z0), ny = min(5, Hn - y0), nx = min(5, Wn - x0);
    const int xe = x0 + nx;            // <= 64
    const int a0 = x0 & ~3;
    const bool need2 = (a0 + 4) < xe;

    float m[8];
    #pragma unroll
    for (int j = 0; j < 8; ++j) {
        int e = a0 + j;
        m[j] = (e >= x0 && e < xe) ? 1.f : 0.f;
    }

    const float* base = fm + ((size_t)(b * Cn + c)) * DHW
                           + (size_t)z0 * HW + (size_t)y0 * Wn;
    float s = 0.f;
    #pragma unroll
    for (int iz = 0; iz < 5; ++iz) {
        #pragma unroll
        for (int iy = 0; iy < 5; ++iy) {
            if (iz < nz && iy < ny) {          // per-lane predication
                const float* row = base + iz * HW + iy * Wn;
                float4 v0 = *(const float4*)(row + a0);
                s = fmaf(v0.x, m[0], s);
                s = fmaf(v0.y, m[1], s);
                s = fmaf(v0.z, m[2], s);
                s = fmaf(v0.w, m[3], s);
                if (need2) {
                    float4 v1 = *(const float4*)(row + a0 + 4);
                    s = fmaf(v1.x, m[4], s);
                    s = fmaf(v1.y, m[5], s);
                    s = fmaf(v1.z, m[6], s);
                    s = fmaf(v1.w, m[7], s);
                }
            }
        }
    }
    vec[((size_t)(b * Kt + k) << 8) + c] = s / (float)(nz * ny * nx);
}

// ---------------- GEMV: feature = vec @ Wp^T + b --------------------------
__global__ __launch_bounds__(256) void gemv_kernel(
        const float* __restrict__ vec, const float* __restrict__ Wp,
        const float* __restrict__ bias, float* __restrict__ out) {
    const int p   = blockIdx.x;        // PROJ
    const int tid = threadIdx.x;       // 256
    const float4* w4 = (const float4*)(Wp + (size_t)p * VECLEN);

    float acc[Bn] = {0.f, 0.f, 0.f, 0.f};
    for (int i = tid; i < VECLEN / 4; i += 256) {
        float4 wv = w4[i];
        #pragma unroll
        for (int bb = 0; bb < Bn; ++bb) {
            float4 vv = ((const float4*)(vec + bb * VECLEN))[i];
            acc[bb] += wv.x * vv.x + wv.y * vv.y + wv.z * vv.z + wv.w * vv.w;
        }
    }

    __shared__ float red[4][Bn];
    const int lane = tid & 63, wave = tid >> 6;
    #pragma unroll
    for (int bb = 0; bb < Bn; ++bb) {
        float v = acc[bb];
        #pragma unroll
        for (int off = 32; off > 0; off >>= 1) v += __shfl_down(v, off, 64);
        if (lane == 0) red[wave][bb] = v;
    }
    __syncthreads();
    if (tid < Bn) {
        int bb = tid;
        float t = red[0][bb] + red[1][bb] + red[2][bb] + red[3][bb];
        out[OUT_FEAT + bb * PROJ + p] = t + bias[p];
    }
}

extern "C" void kernel_launch(void* const* d_in, const int* in_sizes, int n_in,
                              void* d_out, int out_size, void* d_ws, size_t ws_size,
                              hipStream_t stream) {
    const float* fm    = (const float*)d_in[0];
    const float* score = (const float*)d_in[1];
    const float* Wp    = (const float*)d_in[2];
    const float* bias  = (const float*)d_in[3];
    float* out = (float*)d_out;

    char* ws = (char*)d_ws;
    int*   cand_cnt = (int*)(ws + WS_CNT_OFF);
    int*   topk_idx = (int*)(ws + WS_IDX_OFF);
    unsigned long long* cand = (unsigned long long*)(ws + WS_CAND_OFF);
    float* vec      = (float*)(ws + WS_VEC_OFF);

    hipMemsetAsync(cand_cnt, 0, Bn * sizeof(int), stream);
    compact_kernel<<<Bn * 64, 256, 0, stream>>>(score, cand, cand_cnt);
    final_kernel<<<Bn, 512, 0, stream>>>(score, cand, cand_cnt, out, topk_idx);
    gather_kernel<<<Bn * 64, 256, 0, stream>>>(fm, topk_idx, vec);
    gemv_kernel<<<PROJ, 256, 0, stream>>>(vec, Wp, bias, out);
}

// Round 8
// 66.202 us; speedup vs baseline: 1.3168x; 1.0725x over previous
//
#include <hip/hip_runtime.h>
#include <hip/hip_bf16.h>

// Problem constants
#define Bn   4
#define Cn   256
#define Dn   32
#define Hn   64
#define Wn   64
#define Kt   64          // top-k
#define PROJ 512
#define DHW  (Dn*Hn*Wn)  // 131072
#define HW   (Hn*Wn)     // 4096
#define VECLEN (Kt*Cn)   // 16384 per batch

#define NBIN    4096     // fallback histogram bins (top 12 sortable bits)
#define CANDMAX 4096     // fallback candidate cap
#define SLOT    128      // per-compact-block slot stride (u64): [0]=count, 127 usable
#define STATIC_THR 3.0f  // scores ~ N(0,1); top-64/131072 is ~3.24 sigma.
                         // >3.0 keeps ~177/batch. If ever wrong (any block >127
                         // cands, or total <64 or >4096), final_kernel recomputes
                         // exactly -- correctness never depends on the guess.

// ---- workspace layout (bytes) ----
#define WS_CAND_OFF 0            // u64 cand[Bn*64][SLOT] = 256 KB
#define WS_IDX_OFF  (256*1024)   // int topk_idx[Bn*Kt]   = 1 KB
#define WS_VEC_OFF  (260*1024)   // float vec[Bn][VECLEN] = 256 KB

// ---- d_out layout (float32 elements) ----
#define OUT_SCORES 768
#define OUT_FEAT   1024

__device__ __forceinline__ unsigned f2sortable(float f) {
    unsigned u = __float_as_uint(f);
    return (u & 0x80000000u) ? ~u : (u | 0x80000000u);
}
__device__ __forceinline__ float sortable2f(unsigned u) {
    unsigned orig = (u & 0x80000000u) ? (u & 0x7FFFFFFFu) : ~u;
    return __uint_as_float(orig);
}

// ---------------- Pass 1: static-threshold compact into per-block slots --
// grid = Bn*64 = 256 blocks x 256 threads; block owns slot region [blk*SLOT].
// Every block writes its count word unconditionally -> no pre-zero needed.
__global__ __launch_bounds__(256) void compact_kernel(
        const float* __restrict__ score, unsigned long long* __restrict__ cand) {
    __shared__ unsigned long long lc[SLOT - 1];
    __shared__ int lcnt;
    const int blk = blockIdx.x;
    const int b   = blk >> 6;
    const int sub = blk & 63;
    const int tid = threadIdx.x;
    if (tid == 0) lcnt = 0;
    __syncthreads();

    const unsigned thr = f2sortable(STATIC_THR);
    const float4* src = (const float4*)(score + (size_t)b * DHW) + sub * 512;
    #pragma unroll
    for (int i = tid; i < 512; i += 256) {
        float4 v = src[i];
        unsigned gbase = (unsigned)((sub * 512 + i) * 4);
        float vals[4] = {v.x, v.y, v.z, v.w};
        #pragma unroll
        for (int l = 0; l < 4; ++l) {
            unsigned u = f2sortable(vals[l]);
            if (u >= thr) {
                int pos = atomicAdd(&lcnt, 1);
                if (pos < SLOT - 1)
                    lc[pos] = ((unsigned long long)u << 32) |
                              (0xFFFFFFFFu - (gbase + l));
            }
        }
    }
    __syncthreads();

    unsigned long long* cb = cand + (size_t)blk * SLOT;
    int n = lcnt;
    if (n > SLOT - 1) n = SLOT;          // SLOT = overflow marker
    if (tid == 0) cb[0] = (unsigned long long)n;
    int m = (n > SLOT - 1) ? (SLOT - 1) : n;
    for (int i = tid; i < m; i += 256) cb[1 + i] = lc[i];
}

// ---------------- Pass 2: rank-select top-64 (w/ exact fallback) ---------
// grid = Bn x 256 threads. Gather candidates from slots, compute exact rank
// of each unique key by LDS scan (n~177 -> ~177 compares, barrier-free),
// scatter winners into win[rank]. Fallback: exact in-block hist->compact.
__global__ __launch_bounds__(256) void final_kernel(
        const float* __restrict__ score,
        const unsigned long long* __restrict__ cand,
        float* __restrict__ out, int* __restrict__ topk_idx) {
    __shared__ unsigned long long keys[CANDMAX];   // 32 KB
    __shared__ unsigned long long win[Kt];
    __shared__ int lh[NBIN];                       // 16 KB (fallback only)
    __shared__ int partial[256];
    __shared__ int cnts[64], offs[64];
    __shared__ int s_n, s_thr, s_cnt, s_ovf;
    const int b   = blockIdx.x;
    const int tid = threadIdx.x;

    if (tid == 0) { s_ovf = 0; s_cnt = 0; }
    __syncthreads();
    if (tid < 64) {
        int c = (int)cand[(size_t)((b << 6) + tid) * SLOT];
        if (c > SLOT - 1) atomicOr(&s_ovf, 1);
        cnts[tid] = c;
    }
    __syncthreads();
    if (tid == 0) {
        int o = 0;
        for (int s = 0; s < 64; ++s) { offs[s] = o; o += cnts[s]; }
        s_n = o;
    }
    __syncthreads();

    int n = s_n;
    if (!s_ovf && n >= Kt && n <= CANDMAX) {
        // fast path: gather candidates from per-block slots (L2-hot)
        for (int s = 0; s < 64; ++s) {
            int c = cnts[s], o = offs[s];
            const unsigned long long* cb =
                cand + (size_t)((b << 6) + s) * SLOT + 1;
            for (int i = tid; i < c; i += 256) keys[o + i] = cb[i];
        }
        __syncthreads();
    } else {
        // ---- exact fallback: hist -> threshold -> compact, in-block ----
        for (int i = tid; i < NBIN; i += 256) lh[i] = 0;
        __syncthreads();
        const float4* src = (const float4*)(score + (size_t)b * DHW);
        for (int i = tid; i < DHW / 4; i += 256) {
            float4 v = src[i];
            atomicAdd(&lh[f2sortable(v.x) >> 20], 1);
            atomicAdd(&lh[f2sortable(v.y) >> 20], 1);
            atomicAdd(&lh[f2sortable(v.z) >> 20], 1);
            atomicAdd(&lh[f2sortable(v.w) >> 20], 1);
        }
        __syncthreads();
        {
            int base = NBIN - 16 - 16 * tid;
            int s = 0;
            #pragma unroll
            for (int i = 0; i < 16; ++i) s += lh[base + i];
            partial[tid] = s;
        }
        __syncthreads();
        if (tid == 0) {
            int cum = 0, T = 0;
            for (int j = 0; j < 256; ++j) {
                if (cum + partial[j] >= Kt) {
                    int bb = NBIN - 1 - 16 * j;
                    for (int i = 0; i < 16; ++i) {
                        cum += lh[bb - i];
                        if (cum >= Kt) { T = bb - i; break; }
                    }
                    break;
                }
                cum += partial[j];
            }
            s_thr = T;
        }
        __syncthreads();
        const unsigned thr = (unsigned)s_thr;
        for (int i = tid; i < DHW / 4; i += 256) {
            float4 v = src[i];
            float vals[4] = {v.x, v.y, v.z, v.w};
            #pragma unroll
            for (int l = 0; l < 4; ++l) {
                unsigned u = f2sortable(vals[l]);
                if ((u >> 20) >= thr) {
                    int pos = atomicAdd(&s_cnt, 1);
                    if (pos < CANDMAX)
                        keys[pos] = ((unsigned long long)u << 32) |
                                    (0xFFFFFFFFu - (unsigned)(4 * i + l));
                }
            }
        }
        __syncthreads();
        n = s_cnt;
        if (n > CANDMAX) n = CANDMAX;
    }

    // rank selection: keys are unique (idx embedded) -> ranks unique; n >= 64
    for (int i = tid; i < n; i += 256) {
        unsigned long long k = keys[i];
        int r = 0;
        for (int j = 0; j < n; ++j) r += (keys[j] > k);
        if (r < Kt) win[r] = k;
    }
    __syncthreads();

    if (tid < Kt) {
        unsigned long long kk = win[tid];
        float sc = sortable2f((unsigned)(kk >> 32));
        unsigned gidx = 0xFFFFFFFFu - (unsigned)(kk & 0xFFFFFFFFu);
        int z = (int)(gidx >> 12);
        int y = (int)((gidx >> 6) & 63);
        int x = (int)(gidx & 63);
        int o = (b * Kt + tid) * 3;
        out[o + 0] = (float)z;
        out[o + 1] = (float)y;
        out[o + 2] = (float)x;
        out[OUT_SCORES + b * Kt + tid] = sc;
        topk_idx[b * Kt + tid] = (int)gidx;
    }
}

// ---------------- Gather: masked patch average per (b,k,c) ---------------
// Round-4 form (best measured): lane = k -> a wave's 64 simultaneous
// addresses are scattered patch locations (diverse DRAM channel/bank bits).
// Each thread computes the full 125-tap clamped sum for its (b,k,c) with
// ~50 independent float4 loads (deep MLP). grid = Bn*64 x 256.
__global__ __launch_bounds__(256) void gather_kernel(
        const float* __restrict__ fm, const int* __restrict__ topk_idx,
        float* __restrict__ vec) {
    const int blk = blockIdx.x;        // Bn*64 = 256
    const int b   = blk >> 6;
    const int cg  = blk & 63;
    const int tid = threadIdx.x;
    const int k   = tid & 63;          // lane = k
    const int c   = cg * 4 + (tid >> 6);

    const int idx = topk_idx[b * Kt + k];
    const int z = idx >> 12;
    const int y = (idx >> 6) & 63;
    const int x = idx & 63;
    const int z0 = max(z - 2, 0), y0 = max(y - 2, 0), x0 = max(x - 2, 0);
    const int nz = min(5, Dn - z0), ny = min(5, Hn - y0), nx = min(5, Wn - x0);
    const int xe = x0 + nx;            // <= 64
    const int a0 = x0 & ~3;
    const bool need2 = (a0 + 4) < xe;

    float m[8];
    #pragma unroll
    for (int j = 0; j < 8; ++j) {
        int e = a0 + j;
        m[j] = (e >= x0 && e < xe) ? 1.f : 0.f;
    }

    const float* base = fm + ((size_t)(b * Cn + c)) * DHW
                           + (size_t)z0 * HW + (size_t)y0 * Wn;
    float s = 0.f;
    #pragma unroll
    for (int iz = 0; iz < 5; ++iz) {
        #pragma unroll
        for (int iy = 0; iy < 5; ++iy) {
            if (iz < nz && iy < ny) {          // per-lane predication
                const float* row = base + iz * HW + iy * Wn;
                float4 v0 = *(const float4*)(row + a0);
                s = fmaf(v0.x, m[0], s);
                s = fmaf(v0.y, m[1], s);
                s = fmaf(v0.z, m[2], s);
                s = fmaf(v0.w, m[3], s);
                if (need2) {
                    float4 v1 = *(const float4*)(row + a0 + 4);
                    s = fmaf(v1.x, m[4], s);
                    s = fmaf(v1.y, m[5], s);
                    s = fmaf(v1.z, m[6], s);
                    s = fmaf(v1.w, m[7], s);
                }
            }
        }
    }
    vec[((size_t)(b * Kt + k) << 8) + c] = s / (float)(nz * ny * nx);
}

// ---------------- GEMV: feature = vec @ Wp^T + b --------------------------
__global__ __launch_bounds__(256) void gemv_kernel(
        const float* __restrict__ vec, const float* __restrict__ Wp,
        const float* __restrict__ bias, float* __restrict__ out) {
    const int p   = blockIdx.x;        // PROJ
    const int tid = threadIdx.x;       // 256
    const float4* w4 = (const float4*)(Wp + (size_t)p * VECLEN);

    float acc[Bn] = {0.f, 0.f, 0.f, 0.f};
    for (int i = tid; i < VECLEN / 4; i += 256) {
        float4 wv = w4[i];
        #pragma unroll
        for (int bb = 0; bb < Bn; ++bb) {
            float4 vv = ((const float4*)(vec + bb * VECLEN))[i];
            acc[bb] += wv.x * vv.x + wv.y * vv.y + wv.z * vv.z + wv.w * vv.w;
        }
    }

    __shared__ float red[4][Bn];
    const int lane = tid & 63, wave = tid >> 6;
    #pragma unroll
    for (int bb = 0; bb < Bn; ++bb) {
        float v = acc[bb];
        #pragma unroll
        for (int off = 32; off > 0; off >>= 1) v += __shfl_down(v, off, 64);
        if (lane == 0) red[wave][bb] = v;
    }
    __syncthreads();
    if (tid < Bn) {
        int bb = tid;
        float t = red[0][bb] + red[1][bb] + red[2][bb] + red[3][bb];
        out[OUT_FEAT + bb * PROJ + p] = t + bias[p];
    }
}

extern "C" void kernel_launch(void* const* d_in, const int* in_sizes, int n_in,
                              void* d_out, int out_size, void* d_ws, size_t ws_size,
                              hipStream_t stream) {
    const float* fm    = (const float*)d_in[0];
    const float* score = (const float*)d_in[1];
    const float* Wp    = (const float*)d_in[2];
    const float* bias  = (const float*)d_in[3];
    float* out = (float*)d_out;

    char* ws = (char*)d_ws;
    unsigned long long* cand = (unsigned long long*)(ws + WS_CAND_OFF);
    int*   topk_idx = (int*)(ws + WS_IDX_OFF);
    float* vec      = (float*)(ws + WS_VEC_OFF);

    compact_kernel<<<Bn * 64, 256, 0, stream>>>(score, cand);
    final_kernel<<<Bn, 256, 0, stream>>>(score, cand, out, topk_idx);
    gather_kernel<<<Bn * 64, 256, 0, stream>>>(fm, topk_idx, vec);
    gemv_kernel<<<PROJ, 256, 0, stream>>>(vec, Wp, bias, out);
}